// Round 11
// baseline (188.256 us; speedup 1.0000x reference)
//
#include <hip/hip_runtime.h>
#include <stdint.h>
#include <stddef.h>

#define DEV __device__ __forceinline__

typedef unsigned short u16;
typedef __attribute__((ext_vector_type(8))) __bf16 bf16x8;
typedef __attribute__((ext_vector_type(4))) float f32x4;
typedef __attribute__((ext_vector_type(8))) unsigned short u16x8;
typedef __attribute__((ext_vector_type(4))) unsigned short u16x4;

// ---------- helpers ----------
DEV u16 f2bf(float f) {
  uint32_t u = __builtin_bit_cast(uint32_t, f);
  u += 0x7fffu + ((u >> 16) & 1u);  // round-to-nearest-even
  return (u16)(u >> 16);
}
DEV float bf2f(u16 h) {
  uint32_t u = ((uint32_t)h) << 16;
  return __builtin_bit_cast(float, u);
}
DEV f32x4 mfma16(bf16x8 a, bf16x8 b, f32x4 c) {
  return __builtin_amdgcn_mfma_f32_16x16x32_bf16(a, b, c, 0, 0, 0);
}
DEV void ld_lds16(const void* g, void* l) {
  __builtin_amdgcn_global_load_lds((const __attribute__((address_space(1))) void*)g,
                                   (__attribute__((address_space(3))) void*)l, 16, 0, 0);
}

// softmax scale folded into Q: 1/sqrt(64) * log2(e)
#define Q_SCALE 0.18033688011112042f

// ---------- f32 -> bf16 convert, all 5 tensors, 8 elems/thread ----------
// grid: 1536 (x) + 4*288 (weights) = 2688 blocks
__global__ __launch_bounds__(256) void k_cvt_all(const float* __restrict__ x,
                                                 const float* __restrict__ wq,
                                                 const float* __restrict__ wk,
                                                 const float* __restrict__ wv,
                                                 const float* __restrict__ wo,
                                                 u16* __restrict__ dx,
                                                 u16* __restrict__ dqkv,
                                                 u16* __restrict__ dwo) {
  const int bid = blockIdx.x;
  const float* src;
  u16* dst;
  int off;
  if (bid < 1536) {
    src = x; dst = dx; off = bid;
  } else {
    const int t = bid - 1536;
    const int w = t / 288;
    off = t - w * 288;
    src = (w == 0) ? wq : (w == 1) ? wk : (w == 2) ? wv : wo;
    dst = (w < 3) ? (dqkv + (size_t)w * 589824) : dwo;
  }
  const int i = (off * 256 + threadIdx.x) * 8;
  const float4 f0 = *(const float4*)(src + i);
  const float4 f1 = *(const float4*)(src + i + 4);
  u16x8 o;
  o[0] = f2bf(f0.x); o[1] = f2bf(f0.y); o[2] = f2bf(f0.z); o[3] = f2bf(f0.w);
  o[4] = f2bf(f1.x); o[5] = f2bf(f1.y); o[6] = f2bf(f1.z); o[7] = f2bf(f1.w);
  *(u16x8*)(dst + i) = o;
}

// ---------- fused QKV GEMM + RoPE + head relayout + V transpose ----------
// C[4096,2304] = x_bf[4096,768] * wqkv[2304,768]^T, m97 128x128 tile.
// Q/K epilogue stores a PERMUTED head-dim (RoPE pair interleaved, coalesced
// u32 stores); QK^T invariant under shared d-permutation.
__global__ __launch_bounds__(256) void k_gemm_qkv(const u16* __restrict__ A,
                                                  const u16* __restrict__ B,
                                                  const int* __restrict__ row_ids,
                                                  const int* __restrict__ col_ids,
                                                  u16* __restrict__ Qh,
                                                  u16* __restrict__ Kh,
                                                  u16* __restrict__ Vt) {
  const int K = 768;
  __shared__ __align__(16) u16 sA[128 * 64];
  __shared__ __align__(16) u16 sB[128 * 64];
  __shared__ int sIds[256];
  const int tid = threadIdx.x;
  const int lane = tid & 63;
  const int wid = tid >> 6;
  const int wm = wid & 1, wn = wid >> 1;
  const int col16 = lane & 15, quad = lane >> 4;
  const int rowBase = blockIdx.y * 128;
  const int colBase = blockIdx.x * 128;
  const int seg_r = lane >> 3;
  const int seg_c = lane & 7;

  f32x4 zero; zero[0] = zero[1] = zero[2] = zero[3] = 0.0f;
  f32x4 acc[4][4];
#pragma unroll
  for (int i = 0; i < 4; ++i)
#pragma unroll
    for (int j = 0; j < 4; ++j) acc[i][j] = zero;

  for (int k0 = 0; k0 < K; k0 += 64) {
#pragma unroll
    for (int c = 0; c < 4; ++c) {
      const int seg = wid * 4 + c;
      ld_lds16(A + (size_t)(rowBase + seg * 8 + seg_r) * K + k0 + seg_c * 8, sA + seg * 512);
      ld_lds16(B + (size_t)(colBase + seg * 8 + seg_r) * K + k0 + seg_c * 8, sB + seg * 512);
    }
    __syncthreads();
#pragma unroll
    for (int kk = 0; kk < 2; ++kk) {
      bf16x8 af[4], bfr[4];
#pragma unroll
      for (int t = 0; t < 4; ++t) {
        af[t]  = *(const bf16x8*)(sA + (wm * 64 + t * 16 + col16) * 64 + kk * 32 + quad * 8);
        bfr[t] = *(const bf16x8*)(sB + (wn * 64 + t * 16 + col16) * 64 + kk * 32 + quad * 8);
      }
#pragma unroll
      for (int tm = 0; tm < 4; ++tm)
#pragma unroll
        for (int tn = 0; tn < 4; ++tn)
          acc[tm][tn] = mfma16(af[tm], bfr[tn], acc[tm][tn]);
    }
    __syncthreads();
  }

  // ---- epilogue
  const int bx = blockIdx.x;            // 0..17
  const int type = bx / 6;              // 0 Q, 1 K, 2 V
  const int h = (bx % 6) * 2 + wn;      // head 0..11
  const int bb = rowBase >> 11;
  const int s0 = rowBase & 2047;
  const size_t bh = (size_t)bb * 12 + h;

  if (type < 2) {
    if (tid < 128) {
      sIds[tid] = row_ids[s0 + tid];
      sIds[128 + tid] = col_ids[s0 + tid];
    }
    __syncthreads();
    u16* dst = (type == 0) ? Qh : Kh;
    const float scl = (type == 0) ? Q_SCALE : 1.0f;
    const float invf = exp2f(-(float)col16 * 0.8304820237218406f);
#pragma unroll
    for (int tm = 0; tm < 4; ++tm)
#pragma unroll
      for (int r = 0; r < 4; ++r) {
        const int lrow = wm * 64 + tm * 16 + quad * 4 + r;
        const float aR = (float)sIds[lrow] * invf;
        const float aC = (float)sIds[128 + lrow] * invf;
        const float cR = __cosf(aR), sR = __sinf(aR);
        const float cC = __cosf(aC), sC = __sinf(aC);
        const float x1 = acc[tm][0][r], x2 = acc[tm][1][r];
        const float x3 = acc[tm][2][r], x4 = acc[tm][3][r];
        const float y1 = (x1 * cR - x2 * sR) * scl;
        const float y2 = (x2 * cR + x1 * sR) * scl;
        const float y3 = (x3 * cC - x4 * sC) * scl;
        const float y4 = (x4 * cC + x3 * sC) * scl;
        u16* p = dst + (bh * 2048 + s0 + lrow) * 64;
        *(uint32_t*)(p + 2 * col16)      = (uint32_t)f2bf(y1) | ((uint32_t)f2bf(y2) << 16);
        *(uint32_t*)(p + 32 + 2 * col16) = (uint32_t)f2bf(y3) | ((uint32_t)f2bf(y4) << 16);
      }
  } else {
#pragma unroll
    for (int tm = 0; tm < 4; ++tm)
#pragma unroll
      for (int tn = 0; tn < 4; ++tn) {
        const int d = tn * 16 + col16;
        const int srow = s0 + wm * 64 + tm * 16 + quad * 4;
        u16x4 o4;
#pragma unroll
        for (int r = 0; r < 4; ++r) o4[r] = f2bf(acc[tm][tn][r]);
        *(u16x4*)(Vt + (bh * 64 + d) * 2048 + srow) = o4;
      }
  }
}

// ---------- GEMM: C[M,N] = A[M,K]*B[N,K]^T, 64x128 tile (out proj) ----------
// R2-proven: 4 waves side-by-side in N, global_load_lds staging, f32 out.
__global__ __launch_bounds__(256, 4) void k_gemm64(const u16* __restrict__ A,
                                                   const u16* __restrict__ B,
                                                   float* __restrict__ C,
                                                   int N, int K) {
  __shared__ __align__(16) u16 sA[64 * 64];
  __shared__ __align__(16) u16 sB[128 * 64];
  const int tid = threadIdx.x;
  const int lane = tid & 63;
  const int wid = tid >> 6;
  const int col16 = lane & 15, quad = lane >> 4;
  const int rowBase = blockIdx.y * 64;
  const int colBase = blockIdx.x * 128;
  const int seg_r = lane >> 3;
  const int seg_c = lane & 7;

  f32x4 zero; zero[0] = zero[1] = zero[2] = zero[3] = 0.0f;
  f32x4 acc[4][2];
#pragma unroll
  for (int i = 0; i < 4; ++i) { acc[i][0] = zero; acc[i][1] = zero; }

  for (int k0 = 0; k0 < K; k0 += 64) {
#pragma unroll
    for (int c = 0; c < 2; ++c) {
      const int seg = wid * 2 + c;
      ld_lds16(A + (size_t)(rowBase + seg * 8 + seg_r) * K + k0 + seg_c * 8, sA + seg * 512);
    }
#pragma unroll
    for (int c = 0; c < 4; ++c) {
      const int seg = wid * 4 + c;
      ld_lds16(B + (size_t)(colBase + seg * 8 + seg_r) * K + k0 + seg_c * 8, sB + seg * 512);
    }
    __syncthreads();
#pragma unroll
    for (int kk = 0; kk < 2; ++kk) {
      bf16x8 af[4], bfr[2];
#pragma unroll
      for (int t = 0; t < 4; ++t)
        af[t] = *(const bf16x8*)(sA + (t * 16 + col16) * 64 + kk * 32 + quad * 8);
#pragma unroll
      for (int t = 0; t < 2; ++t)
        bfr[t] = *(const bf16x8*)(sB + (wid * 32 + t * 16 + col16) * 64 + kk * 32 + quad * 8);
#pragma unroll
      for (int tm = 0; tm < 4; ++tm)
#pragma unroll
        for (int tn = 0; tn < 2; ++tn)
          acc[tm][tn] = mfma16(af[tm], bfr[tn], acc[tm][tn]);
    }
    __syncthreads();
  }

#pragma unroll
  for (int tm = 0; tm < 4; ++tm)
#pragma unroll
    for (int tn = 0; tn < 2; ++tn)
#pragma unroll
      for (int r = 0; r < 4; ++r) {
        const int row = rowBase + tm * 16 + quad * 4 + r;
        const int col = colBase + wid * 32 + tn * 16 + col16;
        C[(size_t)row * N + col] = acc[tm][tn][r];
      }
}

// ---------- flash attention, causal, split-K (R6 geometry, R7 chain) ----------
// Unit = (head bh, q-tile qt of 64 rows, k-chunk of <=8 64-wide tiles).
// 1920 blocks of 256 thr (4 waves x 16 q-rows). exp2 domain (scale in Q).
// Unconditional rescale (no __any branch), RNE pack.
__global__ __launch_bounds__(256, 3) void k_attn(const u16* __restrict__ Qh,
                                                 const u16* __restrict__ Kh,
                                                 const u16* __restrict__ Vt,
                                                 u16* __restrict__ O,
                                                 u16* __restrict__ Opart,
                                                 float* __restrict__ ml) {
  __shared__ __align__(16) u16 sK[2][64 * 72];
  __shared__ __align__(16) u16 sV[2][64 * 72];
  __shared__ __align__(16) u16 sP[4][16 * 72];
  const int tid = threadIdx.x;
  const int lane = tid & 63;
  const int wid = tid >> 6;
  const int col16 = lane & 15;
  const int quad = lane >> 4;
  // ---- unit decode: bx -> (bh, qt, chunk c)
  const int bx = blockIdx.x;  // 0..1919
  const int bh = bx / 80;
  const int u = bx - bh * 80;
  int qt, c;
  if (u < 8)       { qt = u; c = 0; }
  else if (u < 24) { const int t = u - 8;  qt = 8 + (t >> 1); c = t & 1; }
  else if (u < 48) { const int t = u - 24; const int q3 = t / 3; qt = 16 + q3; c = t - q3 * 3; }
  else             { const int t = u - 48; qt = 24 + (t >> 2); c = t & 3; }
  const int nc = (qt >> 3) + 1;
  const int tile0 = c * 8;
  const int tileE = min(tile0 + 8, qt + 1);
  const int ntiles = tileE - tile0;
  const int b = bh / 12, h = bh % 12;
  const int qw = qt * 64 + wid * 16;  // this wave's first q-row

  const u16* Qb = Qh + (size_t)bh * (2048 * 64);
  const u16* Kb = Kh + (size_t)bh * (2048 * 64);
  const u16* Vb = Vt + (size_t)bh * (64 * 2048);

  // Q B-frags: B[n=qrow=col16][k=quad*8+j], two K=32 halves
  const bf16x8 bQ0 = *(const bf16x8*)(Qb + (size_t)(qw + col16) * 64 + quad * 8);
  const bf16x8 bQ1 = *(const bf16x8*)(Qb + (size_t)(qw + col16) * 64 + 32 + quad * 8);

  f32x4 zero; zero[0] = zero[1] = zero[2] = zero[3] = 0.0f;
  f32x4 o[4];  // O^T: row d = tn*16+quad*4+r, col qrow = col16
#pragma unroll
  for (int i = 0; i < 4; ++i) o[i] = zero;
  float m_r = -1e30f, l_r = 0.0f;

  u16* sPw = &sP[wid][0];

  // ---- cooperative reg staging: 256 thr, K tile 8KB + V tile 8KB, dbuf
  const int sr = tid >> 3;        // 0..31
  const int sc8 = (tid & 7) * 8;  // u16 chunk col
  u16x8 kr[2], vr[2];
  auto gload = [&](int kt) {
#pragma unroll
    for (int i = 0; i < 2; ++i) {
      kr[i] = *(const u16x8*)(Kb + (size_t)(kt + sr + i * 32) * 64 + sc8);
      vr[i] = *(const u16x8*)(Vb + (size_t)(sr + i * 32) * 2048 + kt + sc8);
    }
  };
  auto lwrite = [&](int buf) {
#pragma unroll
    for (int i = 0; i < 2; ++i) {
      *(u16x8*)&sK[buf][(sr + i * 32) * 72 + sc8] = kr[i];
      *(u16x8*)&sV[buf][(sr + i * 32) * 72 + sc8] = vr[i];
    }
  };

  gload(tile0 * 64);
  lwrite(0);
  if (ntiles > 1) gload((tile0 + 1) * 64);
  __syncthreads();

  for (int ki = 0; ki < ntiles; ++ki) {
    const int buf = ki & 1;
    const int kt = (tile0 + ki) * 64;
    if (ki + 1 < ntiles) {
      lwrite(buf ^ 1);
      if (ki + 2 < ntiles) gload((tile0 + ki + 2) * 64);
    }
    // ---- K frags (stride-72 rows)
    bf16x8 ka0[4], ka1[4];
#pragma unroll
    for (int tn = 0; tn < 4; ++tn) {
      const int base = (tn * 16 + col16) * 72 + quad * 8;
      ka0[tn] = *(const bf16x8*)&sK[buf][base];
      ka1[tn] = *(const bf16x8*)&sK[buf][base + 32];
    }
    // ---- S^T = K*Q^T  (row kcol = tn*16+quad*4+r, col qrow = col16)
    f32x4 sc[4];
#pragma unroll
    for (int tn = 0; tn < 4; ++tn)
      sc[tn] = mfma16(ka1[tn], bQ1, mfma16(ka0[tn], bQ0, zero));
    // ---- V frags (latency overlaps softmax)
    bf16x8 va0[4], va1[4];
#pragma unroll
    for (int tn = 0; tn < 4; ++tn) {
      const int base = (tn * 16 + col16) * 72 + quad * 8;
      va0[tn] = *(const bf16x8*)&sV[buf][base];
      va1[tn] = *(const bf16x8*)&sV[buf][base + 32];
    }
    // ---- causal mask (scale pre-folded into Q; only diagonal tile pays)
    if (kt + 63 > qw) {
#pragma unroll
      for (int tn = 0; tn < 4; ++tn)
#pragma unroll
        for (int rr = 0; rr < 4; ++rr)
          if (kt + tn * 16 + quad * 4 + rr > qw + col16) sc[tn][rr] = -1e30f;
    }
    // ---- row max: 15 in-lane fmax + 2 cross-quad shuffles
    float vm = sc[0][0];
#pragma unroll
    for (int tn = 0; tn < 4; ++tn)
#pragma unroll
      for (int rr = 0; rr < 4; ++rr) vm = fmaxf(vm, sc[tn][rr]);
    vm = fmaxf(vm, __shfl_xor(vm, 16, 64));
    vm = fmaxf(vm, __shfl_xor(vm, 32, 64));
    const float mn = fmaxf(m_r, vm);
    const float alpha = exp2f(m_r - mn);
    m_r = mn;
    // ---- P = exp2(S-m), RNE pack -> LDS P^T[qrow][kcol]
    float rs = 0.0f;
#pragma unroll
    for (int tn = 0; tn < 4; ++tn)
#pragma unroll
      for (int h2 = 0; h2 < 2; ++h2) {
        const float p0 = exp2f(sc[tn][2 * h2] - mn);
        const float p1 = exp2f(sc[tn][2 * h2 + 1] - mn);
        rs += p0 + p1;
        const uint32_t w = (uint32_t)f2bf(p0) | ((uint32_t)f2bf(p1) << 16);
        ((uint32_t*)sPw)[col16 * 36 + tn * 8 + quad * 2 + h2] = w;
      }
    rs += __shfl_xor(rs, 16, 64);
    rs += __shfl_xor(rs, 32, 64);
    l_r = l_r * alpha + rs;
    // ---- rescale O^T
#pragma unroll
    for (int t = 0; t < 4; ++t)
#pragma unroll
      for (int rr = 0; rr < 4; ++rr) o[t][rr] *= alpha;
    asm volatile("s_waitcnt lgkmcnt(0)" ::: "memory");  // own P writes visible
    // ---- O^T += V^T * P^T
    const bf16x8 bP0 = *(const bf16x8*)(sPw + col16 * 72 + quad * 8);
    const bf16x8 bP1 = *(const bf16x8*)(sPw + col16 * 72 + 32 + quad * 8);
#pragma unroll
    for (int tn = 0; tn < 4; ++tn)
      o[tn] = mfma16(va1[tn], bP1, mfma16(va0[tn], bP0, o[tn]));
    __syncthreads();  // staged writes visible; buf safe next iter
  }

  if (nc == 1) {
    // ---- final: normalize + store to O
    const float invl = 1.0f / l_r;
    const size_t row = (size_t)b * 2048 + qw + col16;
#pragma unroll
    for (int tn = 0; tn < 4; ++tn)
#pragma unroll
      for (int h2 = 0; h2 < 2; ++h2) {
        const float v0 = o[tn][2 * h2] * invl;
        const float v1 = o[tn][2 * h2 + 1] * invl;
        const uint32_t w = (uint32_t)f2bf(v0) | ((uint32_t)f2bf(v1) << 16);
        const int col = h * 64 + tn * 16 + quad * 4 + 2 * h2;
        *(uint32_t*)(O + row * 768 + col) = w;
      }
  } else {
    // ---- partial: unnormalized O (bf16) + m,l (f32); slot = bx
    u16* op = Opart + (size_t)bx * 4096 + (wid * 16 + col16) * 64;
#pragma unroll
    for (int tn = 0; tn < 4; ++tn)
#pragma unroll
      for (int h2 = 0; h2 < 2; ++h2) {
        const uint32_t w = (uint32_t)f2bf(o[tn][2 * h2]) | ((uint32_t)f2bf(o[tn][2 * h2 + 1]) << 16);
        *(uint32_t*)(op + tn * 16 + quad * 4 + 2 * h2) = w;
      }
    if (quad == 0) {
      float* mlp = ml + (size_t)bx * 128;
      mlp[wid * 16 + col16] = m_r;
      mlp[64 + wid * 16 + col16] = l_r;
    }
  }
}

// ---------- combine partials for qt >= 8 (m in exp2 domain) ----------
__global__ __launch_bounds__(256) void k_combine(const u16* __restrict__ Opart,
                                                 const float* __restrict__ ml,
                                                 u16* __restrict__ O) {
  const int bx = blockIdx.x;
  const int bh = bx / 24;
  const int qt = 8 + (bx - bh * 24);
  const int b = bh / 12, h = bh % 12;
  const int nc = (qt >> 3) + 1;
  const int prefix = (qt < 16) ? (8 + 2 * (qt - 8))
                   : (qt < 24) ? (24 + 3 * (qt - 16))
                               : (48 + 4 * (qt - 24));
  const int slot0 = bh * 80 + prefix;
  const int tid = threadIdx.x;
  const int r = tid >> 2;
  const int d0 = (tid & 3) * 16;

  float m_i[4], w_i[4];
  float M = -1e30f;
  for (int i = 0; i < nc; ++i) {
    m_i[i] = ml[(size_t)(slot0 + i) * 128 + r];
    M = fmaxf(M, m_i[i]);
  }
  float l = 0.0f;
  for (int i = 0; i < nc; ++i) {
    w_i[i] = exp2f(m_i[i] - M);
    l += w_i[i] * ml[(size_t)(slot0 + i) * 128 + 64 + r];
  }
  const float invl = 1.0f / l;

  float a[16];
#pragma unroll
  for (int j = 0; j < 16; ++j) a[j] = 0.0f;
  for (int i = 0; i < nc; ++i) {
    const u16* op = Opart + (size_t)(slot0 + i) * 4096 + r * 64 + d0;
    const u16x8 v0 = *(const u16x8*)op;
    const u16x8 v1 = *(const u16x8*)(op + 8);
#pragma unroll
    for (int j = 0; j < 8; ++j) {
      a[j] += w_i[i] * bf2f(v0[j]);
      a[8 + j] += w_i[i] * bf2f(v1[j]);
    }
  }
  u16x8 o0, o1;
#pragma unroll
  for (int j = 0; j < 8; ++j) {
    o0[j] = f2bf(a[j] * invl);
    o1[j] = f2bf(a[8 + j] * invl);
  }
  u16* dst = O + (size_t)(b * 2048 + qt * 64 + r) * 768 + h * 64 + d0;
  *(u16x8*)dst = o0;
  *(u16x8*)(dst + 8) = o1;
}

// ---------- launch ----------
extern "C" void kernel_launch(void* const* d_in, const int* in_sizes, int n_in,
                              void* d_out, int out_size, void* d_ws, size_t ws_size,
                              hipStream_t stream) {
  const float* x       = (const float*)d_in[0];
  const int*   row_ids = (const int*)d_in[1];
  const int*   col_ids = (const int*)d_in[2];
  const float* Wq      = (const float*)d_in[3];
  const float* Wk      = (const float*)d_in[4];
  const float* Wv      = (const float*)d_in[5];
  const float* Wo      = (const float*)d_in[6];
  float* out = (float*)d_out;

  uint8_t* w8 = (uint8_t*)d_ws;
  u16* x_bf = (u16*)(w8 + 0);         // 4096x768
  u16* wqkv = (u16*)(w8 + 6291456);   // 2304x768
  u16* wo   = (u16*)(w8 + 9830400);   // 768x768
  u16* qh   = (u16*)(w8 + 29884416);  // (24,2048,64)
  u16* kh   = (u16*)(w8 + 36175872);  // (24,2048,64)
  u16* vt   = (u16*)(w8 + 42467328);  // (24,64,2048)
  u16* obuf = (u16*)(w8 + 48758784);  // 4096x768
  u16*   opart = (u16*)(w8 + 11010048);               // 1920 x 64 x 64 bf16
  float* mlbuf = (float*)(w8 + 11010048 + 15728640);  // 1920 x 128 f32

  // 1) convert everything to bf16
  k_cvt_all<<<2688, 256, 0, stream>>>(x, Wq, Wk, Wv, Wo, x_bf, wqkv, wo);
  // 2) fused QKV projection + RoPE (permuted-d) + relayout + V transpose
  k_gemm_qkv<<<dim3(18, 32), 256, 0, stream>>>(x_bf, wqkv, row_ids, col_ids, qh, kh, vt);
  // 3) causal flash attention, split-K
  k_attn<<<1920, 256, 0, stream>>>(qh, kh, vt, obuf, opart, mlbuf);
  // 3b) merge partials for qt >= 8
  k_combine<<<576, 256, 0, stream>>>(opart, mlbuf, obuf);
  // 4) output projection -> f32 (64x128 tile, 384 blocks)
  k_gemm64<<<dim3(6, 64), 256, 0, stream>>>(obuf, wo, out, 768, 768);
}

// Round 12
// 172.585 us; speedup vs baseline: 1.0908x; 1.0908x over previous
//
#include <hip/hip_runtime.h>
#include <stdint.h>
#include <stddef.h>

#define DEV __device__ __forceinline__

typedef unsigned short u16;
typedef __attribute__((ext_vector_type(8))) __bf16 bf16x8;
typedef __attribute__((ext_vector_type(4))) float f32x4;
typedef __attribute__((ext_vector_type(8))) unsigned short u16x8;
typedef __attribute__((ext_vector_type(4))) unsigned short u16x4;

// ---------- helpers ----------
DEV u16 f2bf(float f) {
  uint32_t u = __builtin_bit_cast(uint32_t, f);
  u += 0x7fffu + ((u >> 16) & 1u);  // round-to-nearest-even
  return (u16)(u >> 16);
}
DEV float bf2f(u16 h) {
  uint32_t u = ((uint32_t)h) << 16;
  return __builtin_bit_cast(float, u);
}
DEV f32x4 mfma16(bf16x8 a, bf16x8 b, f32x4 c) {
  return __builtin_amdgcn_mfma_f32_16x16x32_bf16(a, b, c, 0, 0, 0);
}
DEV void ld_lds16(const void* g, void* l) {
  __builtin_amdgcn_global_load_lds((const __attribute__((address_space(1))) void*)g,
                                   (__attribute__((address_space(3))) void*)l, 16, 0, 0);
}

// softmax scale folded into Q: 1/sqrt(64) * log2(e)
#define Q_SCALE 0.18033688011112042f

// ---------- f32 -> bf16 convert, all 5 tensors, 8 elems/thread ----------
__global__ __launch_bounds__(256) void k_cvt_all(const float* __restrict__ x,
                                                 const float* __restrict__ wq,
                                                 const float* __restrict__ wk,
                                                 const float* __restrict__ wv,
                                                 const float* __restrict__ wo,
                                                 u16* __restrict__ dx,
                                                 u16* __restrict__ dqkv,
                                                 u16* __restrict__ dwo) {
  const int bid = blockIdx.x;
  const float* src;
  u16* dst;
  int off;
  if (bid < 1536) {
    src = x; dst = dx; off = bid;
  } else {
    const int t = bid - 1536;
    const int w = t / 288;
    off = t - w * 288;
    src = (w == 0) ? wq : (w == 1) ? wk : (w == 2) ? wv : wo;
    dst = (w < 3) ? (dqkv + (size_t)w * 589824) : dwo;
  }
  const int i = (off * 256 + threadIdx.x) * 8;
  const float4 f0 = *(const float4*)(src + i);
  const float4 f1 = *(const float4*)(src + i + 4);
  u16x8 o;
  o[0] = f2bf(f0.x); o[1] = f2bf(f0.y); o[2] = f2bf(f0.z); o[3] = f2bf(f0.w);
  o[4] = f2bf(f1.x); o[5] = f2bf(f1.y); o[6] = f2bf(f1.z); o[7] = f2bf(f1.w);
  *(u16x8*)(dst + i) = o;
}

// ---------- fused QKV GEMM + RoPE + relayout, 64x128 tile (1152 blocks) ----------
// C[4096,2304] = x_bf * wqkv^T. 4 waves side-by-side in N: wave = 64x32 output
// strip = one half of one head. RoPE pair (d,d+16) = (tn=0,tn=1) of one acc row
// (in-lane). Q/K stored with PERMUTED head-dim (pair interleaved, coalesced u32
// stores); QK^T invariant under shared d-permutation. V stored transposed.
__global__ __launch_bounds__(256, 4) void k_gemm_qkv(const u16* __restrict__ A,
                                                     const u16* __restrict__ B,
                                                     const int* __restrict__ row_ids,
                                                     const int* __restrict__ col_ids,
                                                     u16* __restrict__ Qh,
                                                     u16* __restrict__ Kh,
                                                     u16* __restrict__ Vt) {
  const int K = 768;
  __shared__ __align__(16) u16 sA[64 * 64];
  __shared__ __align__(16) u16 sB[128 * 64];
  __shared__ int sIds[128];
  const int tid = threadIdx.x;
  const int lane = tid & 63;
  const int wid = tid >> 6;
  const int col16 = lane & 15, quad = lane >> 4;
  const int rowBase = blockIdx.y * 64;
  const int colBase = blockIdx.x * 128;
  const int seg_r = lane >> 3;
  const int seg_c = lane & 7;

  f32x4 zero; zero[0] = zero[1] = zero[2] = zero[3] = 0.0f;
  f32x4 acc[4][2];
#pragma unroll
  for (int i = 0; i < 4; ++i) { acc[i][0] = zero; acc[i][1] = zero; }

  for (int k0 = 0; k0 < K; k0 += 64) {
#pragma unroll
    for (int c = 0; c < 2; ++c) {
      const int seg = wid * 2 + c;
      ld_lds16(A + (size_t)(rowBase + seg * 8 + seg_r) * K + k0 + seg_c * 8, sA + seg * 512);
    }
#pragma unroll
    for (int c = 0; c < 4; ++c) {
      const int seg = wid * 4 + c;
      ld_lds16(B + (size_t)(colBase + seg * 8 + seg_r) * K + k0 + seg_c * 8, sB + seg * 512);
    }
    __syncthreads();
#pragma unroll
    for (int kk = 0; kk < 2; ++kk) {
      bf16x8 af[4], bfr[2];
#pragma unroll
      for (int t = 0; t < 4; ++t)
        af[t] = *(const bf16x8*)(sA + (t * 16 + col16) * 64 + kk * 32 + quad * 8);
#pragma unroll
      for (int t = 0; t < 2; ++t)
        bfr[t] = *(const bf16x8*)(sB + (wid * 32 + t * 16 + col16) * 64 + kk * 32 + quad * 8);
#pragma unroll
      for (int tm = 0; tm < 4; ++tm)
#pragma unroll
        for (int tn = 0; tn < 2; ++tn)
          acc[tm][tn] = mfma16(af[tm], bfr[tn], acc[tm][tn]);
    }
    __syncthreads();
  }

  // ---- epilogue
  const int bx = blockIdx.x;            // 0..17
  const int type = bx / 6;              // 0 Q, 1 K, 2 V
  const int h = (bx % 6) * 2 + (wid >> 1);  // head 0..11
  const int half = wid & 1;             // 0: dims 0..31 (row rope), 1: 32..63 (col)
  const int bb = rowBase >> 11;
  const int s0 = rowBase & 2047;
  const size_t bh = (size_t)bb * 12 + h;

  if (type < 2) {
    if (tid < 64) sIds[tid] = row_ids[s0 + tid];
    else if (tid < 128) sIds[tid] = col_ids[s0 + tid - 64];
    __syncthreads();
    u16* dst = (type == 0) ? Qh : Kh;
    const float scl = (type == 0) ? Q_SCALE : 1.0f;
    const float invf = exp2f(-(float)col16 * 0.8304820237218406f);
    const int idOff = half * 64;
#pragma unroll
    for (int tm = 0; tm < 4; ++tm)
#pragma unroll
      for (int r = 0; r < 4; ++r) {
        const int lrow = tm * 16 + quad * 4 + r;
        const float ang = (float)sIds[idOff + lrow] * invf;
        const float cs = __cosf(ang), sn = __sinf(ang);
        const float x1 = acc[tm][0][r], x2 = acc[tm][1][r];
        const float y1 = (x1 * cs - x2 * sn) * scl;
        const float y2 = (x2 * cs + x1 * sn) * scl;
        u16* p = dst + (bh * 2048 + s0 + lrow) * 64;
        *(uint32_t*)(p + half * 32 + 2 * col16) =
            (uint32_t)f2bf(y1) | ((uint32_t)f2bf(y2) << 16);
      }
  } else {
#pragma unroll
    for (int tm = 0; tm < 4; ++tm)
#pragma unroll
      for (int tn = 0; tn < 2; ++tn) {
        const int d = half * 32 + tn * 16 + col16;
        const int srow = s0 + tm * 16 + quad * 4;
        u16x4 o4;
#pragma unroll
        for (int r = 0; r < 4; ++r) o4[r] = f2bf(acc[tm][tn][r]);
        *(u16x4*)(Vt + (bh * 64 + d) * 2048 + srow) = o4;
      }
  }
}

// ---------- GEMM: 64x64 tile, padded-LDS reg staging (out proj, 768 blocks) ----------
__global__ __launch_bounds__(256, 3) void k_gemm_o(const u16* __restrict__ A,
                                                   const u16* __restrict__ B,
                                                   float* __restrict__ C,
                                                   int N, int K) {
  __shared__ __align__(16) u16 sA[64 * 72];
  __shared__ __align__(16) u16 sB[64 * 72];
  const int tid = threadIdx.x;
  const int lane = tid & 63;
  const int wid = tid >> 6;
  const int col16 = lane & 15, quad = lane >> 4;
  const int wm = wid & 1, wn = wid >> 1;
  const int rowBase = blockIdx.y * 64;
  const int colBase = blockIdx.x * 64;
  const int sr = tid >> 3;
  const int sc8 = (tid & 7) * 8;

  f32x4 zero; zero[0] = zero[1] = zero[2] = zero[3] = 0.0f;
  f32x4 acc[2][2];
  acc[0][0] = zero; acc[0][1] = zero; acc[1][0] = zero; acc[1][1] = zero;

  u16x8 ar[2], br[2];
  auto gload = [&](int k0) {
    ar[0] = *(const u16x8*)(A + (size_t)(rowBase + sr) * K + k0 + sc8);
    ar[1] = *(const u16x8*)(A + (size_t)(rowBase + 32 + sr) * K + k0 + sc8);
    br[0] = *(const u16x8*)(B + (size_t)(colBase + sr) * K + k0 + sc8);
    br[1] = *(const u16x8*)(B + (size_t)(colBase + 32 + sr) * K + k0 + sc8);
  };

  gload(0);
  for (int k0 = 0; k0 < K; k0 += 64) {
    __syncthreads();
    *(u16x8*)&sA[sr * 72 + sc8] = ar[0];
    *(u16x8*)&sA[(32 + sr) * 72 + sc8] = ar[1];
    *(u16x8*)&sB[sr * 72 + sc8] = br[0];
    *(u16x8*)&sB[(32 + sr) * 72 + sc8] = br[1];
    if (k0 + 64 < K) gload(k0 + 64);
    __syncthreads();
#pragma unroll
    for (int kk = 0; kk < 2; ++kk) {
      bf16x8 af[2], bfr[2];
#pragma unroll
      for (int t = 0; t < 2; ++t) {
        af[t]  = *(const bf16x8*)&sA[(wm * 32 + t * 16 + col16) * 72 + kk * 32 + quad * 8];
        bfr[t] = *(const bf16x8*)&sB[(wn * 32 + t * 16 + col16) * 72 + kk * 32 + quad * 8];
      }
#pragma unroll
      for (int tm = 0; tm < 2; ++tm)
#pragma unroll
        for (int tn = 0; tn < 2; ++tn)
          acc[tm][tn] = mfma16(af[tm], bfr[tn], acc[tm][tn]);
    }
  }

#pragma unroll
  for (int tm = 0; tm < 2; ++tm)
#pragma unroll
    for (int tn = 0; tn < 2; ++tn)
#pragma unroll
      for (int r = 0; r < 4; ++r) {
        const int row = rowBase + wm * 32 + tm * 16 + quad * 4 + r;
        const int col = colBase + wn * 32 + tn * 16 + col16;
        C[(size_t)row * N + col] = acc[tm][tn][r];
      }
}

// ---------- flash attention, causal, split-K (R6 geometry, R11 chain) ----------
__global__ __launch_bounds__(256, 3) void k_attn(const u16* __restrict__ Qh,
                                                 const u16* __restrict__ Kh,
                                                 const u16* __restrict__ Vt,
                                                 u16* __restrict__ O,
                                                 u16* __restrict__ Opart,
                                                 float* __restrict__ ml) {
  __shared__ __align__(16) u16 sK[2][64 * 72];
  __shared__ __align__(16) u16 sV[2][64 * 72];
  __shared__ __align__(16) u16 sP[4][16 * 72];
  const int tid = threadIdx.x;
  const int lane = tid & 63;
  const int wid = tid >> 6;
  const int col16 = lane & 15;
  const int quad = lane >> 4;
  const int bx = blockIdx.x;  // 0..1919
  const int bh = bx / 80;
  const int u = bx - bh * 80;
  int qt, c;
  if (u < 8)       { qt = u; c = 0; }
  else if (u < 24) { const int t = u - 8;  qt = 8 + (t >> 1); c = t & 1; }
  else if (u < 48) { const int t = u - 24; const int q3 = t / 3; qt = 16 + q3; c = t - q3 * 3; }
  else             { const int t = u - 48; qt = 24 + (t >> 2); c = t & 3; }
  const int nc = (qt >> 3) + 1;
  const int tile0 = c * 8;
  const int tileE = min(tile0 + 8, qt + 1);
  const int ntiles = tileE - tile0;
  const int b = bh / 12, h = bh % 12;
  const int qw = qt * 64 + wid * 16;

  const u16* Qb = Qh + (size_t)bh * (2048 * 64);
  const u16* Kb = Kh + (size_t)bh * (2048 * 64);
  const u16* Vb = Vt + (size_t)bh * (64 * 2048);

  const bf16x8 bQ0 = *(const bf16x8*)(Qb + (size_t)(qw + col16) * 64 + quad * 8);
  const bf16x8 bQ1 = *(const bf16x8*)(Qb + (size_t)(qw + col16) * 64 + 32 + quad * 8);

  f32x4 zero; zero[0] = zero[1] = zero[2] = zero[3] = 0.0f;
  f32x4 o[4];
#pragma unroll
  for (int i = 0; i < 4; ++i) o[i] = zero;
  float m_r = -1e30f, l_r = 0.0f;

  u16* sPw = &sP[wid][0];

  const int sr = tid >> 3;
  const int sc8 = (tid & 7) * 8;
  u16x8 kr[2], vr[2];
  auto gload = [&](int kt) {
#pragma unroll
    for (int i = 0; i < 2; ++i) {
      kr[i] = *(const u16x8*)(Kb + (size_t)(kt + sr + i * 32) * 64 + sc8);
      vr[i] = *(const u16x8*)(Vb + (size_t)(sr + i * 32) * 2048 + kt + sc8);
    }
  };
  auto lwrite = [&](int buf) {
#pragma unroll
    for (int i = 0; i < 2; ++i) {
      *(u16x8*)&sK[buf][(sr + i * 32) * 72 + sc8] = kr[i];
      *(u16x8*)&sV[buf][(sr + i * 32) * 72 + sc8] = vr[i];
    }
  };

  gload(tile0 * 64);
  lwrite(0);
  if (ntiles > 1) gload((tile0 + 1) * 64);
  __syncthreads();

  for (int ki = 0; ki < ntiles; ++ki) {
    const int buf = ki & 1;
    const int kt = (tile0 + ki) * 64;
    if (ki + 1 < ntiles) {
      lwrite(buf ^ 1);
      if (ki + 2 < ntiles) gload((tile0 + ki + 2) * 64);
    }
    bf16x8 ka0[4], ka1[4];
#pragma unroll
    for (int tn = 0; tn < 4; ++tn) {
      const int base = (tn * 16 + col16) * 72 + quad * 8;
      ka0[tn] = *(const bf16x8*)&sK[buf][base];
      ka1[tn] = *(const bf16x8*)&sK[buf][base + 32];
    }
    f32x4 sc[4];
#pragma unroll
    for (int tn = 0; tn < 4; ++tn)
      sc[tn] = mfma16(ka1[tn], bQ1, mfma16(ka0[tn], bQ0, zero));
    bf16x8 va0[4], va1[4];
#pragma unroll
    for (int tn = 0; tn < 4; ++tn) {
      const int base = (tn * 16 + col16) * 72 + quad * 8;
      va0[tn] = *(const bf16x8*)&sV[buf][base];
      va1[tn] = *(const bf16x8*)&sV[buf][base + 32];
    }
    if (kt + 63 > qw) {
#pragma unroll
      for (int tn = 0; tn < 4; ++tn)
#pragma unroll
        for (int rr = 0; rr < 4; ++rr)
          if (kt + tn * 16 + quad * 4 + rr > qw + col16) sc[tn][rr] = -1e30f;
    }
    float vm = sc[0][0];
#pragma unroll
    for (int tn = 0; tn < 4; ++tn)
#pragma unroll
      for (int rr = 0; rr < 4; ++rr) vm = fmaxf(vm, sc[tn][rr]);
    vm = fmaxf(vm, __shfl_xor(vm, 16, 64));
    vm = fmaxf(vm, __shfl_xor(vm, 32, 64));
    const float mn = fmaxf(m_r, vm);
    const float alpha = exp2f(m_r - mn);
    m_r = mn;
    float rs = 0.0f;
#pragma unroll
    for (int tn = 0; tn < 4; ++tn)
#pragma unroll
      for (int h2 = 0; h2 < 2; ++h2) {
        const float p0 = exp2f(sc[tn][2 * h2] - mn);
        const float p1 = exp2f(sc[tn][2 * h2 + 1] - mn);
        rs += p0 + p1;
        const uint32_t w = (uint32_t)f2bf(p0) | ((uint32_t)f2bf(p1) << 16);
        ((uint32_t*)sPw)[col16 * 36 + tn * 8 + quad * 2 + h2] = w;
      }
    rs += __shfl_xor(rs, 16, 64);
    rs += __shfl_xor(rs, 32, 64);
    l_r = l_r * alpha + rs;
#pragma unroll
    for (int t = 0; t < 4; ++t)
#pragma unroll
      for (int rr = 0; rr < 4; ++rr) o[t][rr] *= alpha;
    asm volatile("s_waitcnt lgkmcnt(0)" ::: "memory");
    const bf16x8 bP0 = *(const bf16x8*)(sPw + col16 * 72 + quad * 8);
    const bf16x8 bP1 = *(const bf16x8*)(sPw + col16 * 72 + 32 + quad * 8);
#pragma unroll
    for (int tn = 0; tn < 4; ++tn)
      o[tn] = mfma16(va1[tn], bP1, mfma16(va0[tn], bP0, o[tn]));
    __syncthreads();
  }

  if (nc == 1) {
    const float invl = 1.0f / l_r;
    const size_t row = (size_t)b * 2048 + qw + col16;
#pragma unroll
    for (int tn = 0; tn < 4; ++tn)
#pragma unroll
      for (int h2 = 0; h2 < 2; ++h2) {
        const float v0 = o[tn][2 * h2] * invl;
        const float v1 = o[tn][2 * h2 + 1] * invl;
        const uint32_t w = (uint32_t)f2bf(v0) | ((uint32_t)f2bf(v1) << 16);
        const int col = h * 64 + tn * 16 + quad * 4 + 2 * h2;
        *(uint32_t*)(O + row * 768 + col) = w;
      }
  } else {
    u16* op = Opart + (size_t)bx * 4096 + (wid * 16 + col16) * 64;
#pragma unroll
    for (int tn = 0; tn < 4; ++tn)
#pragma unroll
      for (int h2 = 0; h2 < 2; ++h2) {
        const uint32_t w = (uint32_t)f2bf(o[tn][2 * h2]) | ((uint32_t)f2bf(o[tn][2 * h2 + 1]) << 16);
        *(uint32_t*)(op + tn * 16 + quad * 4 + 2 * h2) = w;
      }
    if (quad == 0) {
      float* mlp = ml + (size_t)bx * 128;
      mlp[wid * 16 + col16] = m_r;
      mlp[64 + wid * 16 + col16] = l_r;
    }
  }
}

// ---------- combine partials for qt >= 8 (m in exp2 domain) ----------
__global__ __launch_bounds__(256) void k_combine(const u16* __restrict__ Opart,
                                                 const float* __restrict__ ml,
                                                 u16* __restrict__ O) {
  const int bx = blockIdx.x;
  const int bh = bx / 24;
  const int qt = 8 + (bx - bh * 24);
  const int b = bh / 12, h = bh % 12;
  const int nc = (qt >> 3) + 1;
  const int prefix = (qt < 16) ? (8 + 2 * (qt - 8))
                   : (qt < 24) ? (24 + 3 * (qt - 16))
                               : (48 + 4 * (qt - 24));
  const int slot0 = bh * 80 + prefix;
  const int tid = threadIdx.x;
  const int r = tid >> 2;
  const int d0 = (tid & 3) * 16;

  float m_i[4], w_i[4];
  float M = -1e30f;
  for (int i = 0; i < nc; ++i) {
    m_i[i] = ml[(size_t)(slot0 + i) * 128 + r];
    M = fmaxf(M, m_i[i]);
  }
  float l = 0.0f;
  for (int i = 0; i < nc; ++i) {
    w_i[i] = exp2f(m_i[i] - M);
    l += w_i[i] * ml[(size_t)(slot0 + i) * 128 + 64 + r];
  }
  const float invl = 1.0f / l;

  float a[16];
#pragma unroll
  for (int j = 0; j < 16; ++j) a[j] = 0.0f;
  for (int i = 0; i < nc; ++i) {
    const u16* op = Opart + (size_t)(slot0 + i) * 4096 + r * 64 + d0;
    const u16x8 v0 = *(const u16x8*)op;
    const u16x8 v1 = *(const u16x8*)(op + 8);
#pragma unroll
    for (int j = 0; j < 8; ++j) {
      a[j] += w_i[i] * bf2f(v0[j]);
      a[8 + j] += w_i[i] * bf2f(v1[j]);
    }
  }
  u16x8 o0, o1;
#pragma unroll
  for (int j = 0; j < 8; ++j) {
    o0[j] = f2bf(a[j] * invl);
    o1[j] = f2bf(a[8 + j] * invl);
  }
  u16* dst = O + (size_t)(b * 2048 + qt * 64 + r) * 768 + h * 64 + d0;
  *(u16x8*)dst = o0;
  *(u16x8*)(dst + 8) = o1;
}

// ---------- launch ----------
extern "C" void kernel_launch(void* const* d_in, const int* in_sizes, int n_in,
                              void* d_out, int out_size, void* d_ws, size_t ws_size,
                              hipStream_t stream) {
  const float* x       = (const float*)d_in[0];
  const int*   row_ids = (const int*)d_in[1];
  const int*   col_ids = (const int*)d_in[2];
  const float* Wq      = (const float*)d_in[3];
  const float* Wk      = (const float*)d_in[4];
  const float* Wv      = (const float*)d_in[5];
  const float* Wo      = (const float*)d_in[6];
  float* out = (float*)d_out;

  uint8_t* w8 = (uint8_t*)d_ws;
  u16* x_bf = (u16*)(w8 + 0);         // 4096x768
  u16* wqkv = (u16*)(w8 + 6291456);   // 2304x768
  u16* wo   = (u16*)(w8 + 9830400);   // 768x768
  u16* qh   = (u16*)(w8 + 29884416);  // (24,2048,64)
  u16* kh   = (u16*)(w8 + 36175872);  // (24,2048,64)
  u16* vt   = (u16*)(w8 + 42467328);  // (24,64,2048)
  u16* obuf = (u16*)(w8 + 48758784);  // 4096x768
  u16*   opart = (u16*)(w8 + 11010048);               // 1920 x 64 x 64 bf16
  float* mlbuf = (float*)(w8 + 11010048 + 15728640);  // 1920 x 128 f32

  // 1) convert everything to bf16
  k_cvt_all<<<2688, 256, 0, stream>>>(x, Wq, Wk, Wv, Wo, x_bf, wqkv, wo);
  // 2) fused QKV projection + RoPE (permuted-d) + relayout, 64x128 tiles
  k_gemm_qkv<<<dim3(18, 64), 256, 0, stream>>>(x_bf, wqkv, row_ids, col_ids, qh, kh, vt);
  // 3) causal flash attention, split-K
  k_attn<<<1920, 256, 0, stream>>>(qh, kh, vt, obuf, opart, mlbuf);
  // 3b) merge partials for qt >= 8
  k_combine<<<576, 256, 0, stream>>>(opart, mlbuf, obuf);
  // 4) output projection -> f32 (64x64 tile, 768 blocks)
  k_gemm_o<<<dim3(12, 64), 256, 0, stream>>>(obuf, wo, out, 768, 768);
}